// Round 1
// baseline (706.512 us; speedup 1.0000x reference)
//
#include <hip/hip_runtime.h>

#define NLEV 5
#define B_   16
#define S_   4096
#define D_   128
#define P_   4096
#define CTOT 496           // total waves across levels: 16+32+64+128+256
#define BP   (B_ * CTOT)   // 7936

// ---------------------------------------------------------------------------
// Pack W_dec_l [D][n_l] (level-major concat) into wdp[w][d] (w-major, 496x128)
// ---------------------------------------------------------------------------
__global__ void pack_wdec(const float* __restrict__ w0, const float* __restrict__ w1,
                          const float* __restrict__ w2, const float* __restrict__ w3,
                          const float* __restrict__ w4, float* __restrict__ wdp)
{
    int idx = blockIdx.x * 256 + threadIdx.x;
    if (idx >= CTOT * D_) return;
    int w = idx >> 7, d = idx & 127;
    const float* src; int off, nl;
    if (w < 16)       { src = w0; off = 0;   nl = 16;  }
    else if (w < 48)  { src = w1; off = 16;  nl = 32;  }
    else if (w < 112) { src = w2; off = 48;  nl = 64;  }
    else if (w < 240) { src = w3; off = 112; nl = 128; }
    else              { src = w4; off = 240; nl = 256; }
    wdp[w * D_ + d] = src[d * nl + (w - off)];
}

// ---------------------------------------------------------------------------
// Encoder: per level. GEMM C[t,c] = sum_d kv[b,t,d] * Wenc[c,d], fused
// weighted reduction over t into acc[kind][b][coff+local] via atomics.
//   block: 256 thr = 8 c-groups (tx) x 32 t-groups (ty); thread tile 8c x 4t
//   tile: 64 c x 128 t; kv staged in LDS transposed [d][t] with XOR swizzle
// ---------------------------------------------------------------------------
__global__ __launch_bounds__(256) void encoder(
    const float* __restrict__ kv, const float* __restrict__ Wenc,
    const float* __restrict__ basef, const int* __restrict__ positions,
    float* __restrict__ acc, int n, int Seff, int coff, float alpha, float l2m)
{
    __shared__ float kvl[128 * 128];   // [d][t^] swizzled, 64 KB
    const int b   = blockIdx.z;
    const int t0  = (S_ - Seff) + blockIdx.y * 128;
    const int c0  = blockIdx.x * 64;
    const int tid = threadIdx.x;
    const int C   = 3 * n;

    // stage kv tile (coalesced global read, swizzled transposed LDS write)
    const float* src = kv + (size_t)(b * S_ + t0) * D_;
    #pragma unroll
    for (int f = 0; f < 16; ++f) {
        int idx = f * 256 + tid;
        int r = idx >> 5, c4 = idx & 31;          // r: local t, c4: d/4
        float4 val = *(const float4*)(src + r * D_ + c4 * 4);
        int d  = c4 * 4;
        int rs = r ^ ((c4 & 7) << 2);             // swizzle: t ^ (((d>>2)&7)<<2)
        kvl[(d + 0) * 128 + rs] = val.x;
        kvl[(d + 1) * 128 + rs] = val.y;
        kvl[(d + 2) * 128 + rs] = val.z;
        kvl[(d + 3) * 128 + rs] = val.w;
    }
    __syncthreads();

    const int tx = tid & 7, ty = tid >> 3;
    const int cl0 = tx * 8, tl0 = ty * 4;
    float accr[4][8];
    #pragma unroll
    for (int i = 0; i < 4; ++i)
        #pragma unroll
        for (int j = 0; j < 8; ++j) accr[i][j] = 0.0f;

    for (int d4 = 0; d4 < 128; d4 += 4) {
        const int swz = ((d4 >> 2) & 7) << 2;
        const int tl  = tl0 ^ swz;                 // same swizzle for d4..d4+3
        const float4 k0 = *(const float4*)(kvl + (d4 + 0) * 128 + tl);
        const float4 k1 = *(const float4*)(kvl + (d4 + 1) * 128 + tl);
        const float4 k2 = *(const float4*)(kvl + (d4 + 2) * 128 + tl);
        const float4 k3 = *(const float4*)(kvl + (d4 + 3) * 128 + tl);
        #pragma unroll
        for (int j = 0; j < 8; ++j) {
            int c = c0 + cl0 + j;
            float4 w = (c < C) ? *(const float4*)(Wenc + (size_t)c * D_ + d4)
                               : make_float4(0.f, 0.f, 0.f, 0.f);
            accr[0][j] += k0.x * w.x + k1.x * w.y + k2.x * w.z + k3.x * w.w;
            accr[1][j] += k0.y * w.x + k1.y * w.y + k2.y * w.z + k3.y * w.w;
            accr[2][j] += k0.z * w.x + k1.z * w.y + k2.z * w.z + k3.z * w.w;
            accr[3][j] += k0.w * w.x + k1.w * w.y + k2.w * w.z + k3.w * w.w;
        }
    }

    // epilogue: apply per-t weight (+ pos_signal / abs per column class),
    // reduce over this thread's 4 t's
    float part[8];
    #pragma unroll
    for (int j = 0; j < 8; ++j) part[j] = 0.0f;
    #pragma unroll
    for (int i = 0; i < 4; ++i) {
        int   tg = t0 + tl0 + i;
        float wt = alpha * exp2f((float)(S_ - 1 - tg) * l2m);
        float pf = (float)positions[tg] * (1.0f / 4096.0f);
        #pragma unroll
        for (int j = 0; j < 8; ++j) {
            int   c  = c0 + cl0 + j;
            float vv = accr[i][j];
            float x;
            if (c < n)          x = vv * sinpif(basef[c < n ? c : 0] * pf);
            else if (c < 2 * n) x = fabsf(vv);
            else                x = vv;
            part[j] += wt * x;
        }
    }

    // cross-ty tree reduction in LDS (reuse kvl), then one atomic per column
    __syncthreads();
    float* scratch = kvl;                         // [64 c][32 ty]
    #pragma unroll
    for (int j = 0; j < 8; ++j) scratch[(cl0 + j) * 32 + ty] = part[j];
    __syncthreads();
    for (int s = 16; s > 0; s >>= 1) {
        if (ty < s) {
            #pragma unroll
            for (int j = 0; j < 8; ++j)
                scratch[(cl0 + j) * 32 + ty] += scratch[(cl0 + j) * 32 + ty + s];
        }
        __syncthreads();
    }
    if (ty == 0) {
        #pragma unroll
        for (int j = 0; j < 8; ++j) {
            int c = c0 + cl0 + j;
            if (c < C) {
                int kind = (c < n) ? 0 : ((c < 2 * n) ? 1 : 2);
                int loc  = c - kind * n;
                atomicAdd(acc + (size_t)kind * BP + b * CTOT + coff + loc,
                          scratch[(cl0 + j) * 32]);
            }
        }
    }
}

// ---------------------------------------------------------------------------
// Combine: per (b,w): A = amp, Q = freq+base, PHI = phase/pi
// ---------------------------------------------------------------------------
__global__ void combine(const float* __restrict__ acc, float* __restrict__ params,
                        const float* __restrict__ b0, const float* __restrict__ b1,
                        const float* __restrict__ b2, const float* __restrict__ b3,
                        const float* __restrict__ b4)
{
    int idx = blockIdx.x * 256 + threadIdx.x;
    if (idx >= BP) return;
    int b = idx / CTOT, w = idx % CTOT;
    const float* bf; int off;
    if (w < 16)       { bf = b0; off = 0;   }
    else if (w < 48)  { bf = b1; off = 16;  }
    else if (w < 112) { bf = b2; off = 48;  }
    else if (w < 240) { bf = b3; off = 112; }
    else              { bf = b4; off = 240; }
    float f  = acc[0 * BP + b * CTOT + w];
    float a  = acc[1 * BP + b * CTOT + w];
    float ph = acc[2 * BP + b * CTOT + w];
    params[0 * BP + b * CTOT + w] = a;                      // A
    params[1 * BP + b * CTOT + w] = f + bf[w - off];        // Q (freq+base)
    params[2 * BP + b * CTOT + w] = ph * 0.31830988618379067f; // PHI/pi
}

// ---------------------------------------------------------------------------
// Decoder: out[b,p,d] = sum_w A*sinpi(Q*rp/4096 + PHI) * wdp[w][d]
//   block: 256 thr, tile 64p x 128d, thread tile 4p x 8d, w in 2 passes of 248
//   v[w][p] staged in LDS (63.5 KB) -> 2 blocks/CU
// ---------------------------------------------------------------------------
__global__ __launch_bounds__(256) void decoder(
    const float* __restrict__ params, const float* __restrict__ wdp,
    const int* __restrict__ rpos, float* __restrict__ out)
{
    __shared__ float v[248 * 64];
    __shared__ float rpn[64];
    const int b     = blockIdx.y;
    const int p0blk = blockIdx.x * 64;
    const int tid   = threadIdx.x;
    if (tid < 64) rpn[tid] = (float)rpos[p0blk + tid] * (1.0f / 4096.0f);

    const float* PA = params + 0 * BP + b * CTOT;
    const float* PQ = params + 1 * BP + b * CTOT;
    const float* PF = params + 2 * BP + b * CTOT;

    const int tx = tid & 15, ty = tid >> 4;
    const int d0 = tx * 8, pl0 = ty * 4;

    float accd[4][8];
    #pragma unroll
    for (int i = 0; i < 4; ++i)
        #pragma unroll
        for (int j = 0; j < 8; ++j) accd[i][j] = 0.0f;

    for (int pass = 0; pass < 2; ++pass) {
        const int wbase = pass * 248;
        __syncthreads();   // also covers rpn init on first pass
        // phase A: compute v[w][p]
        for (int i = 0; i < 62; ++i) {
            int idx = i * 256 + tid;
            int wl = idx >> 6, p = idx & 63;
            int w  = wbase + wl;
            float x = fmaf(PQ[w], rpn[p], PF[w]);
            v[wl * 64 + p] = PA[w] * sinpif(x);
        }
        __syncthreads();
        // phase B: GEMM
        #pragma unroll 2
        for (int wl = 0; wl < 248; ++wl) {
            float vr[4], wr[8];
            *(float4*)&vr[0] = *(const float4*)(v + wl * 64 + pl0);
            *(float4*)&wr[0] = *(const float4*)(wdp + (size_t)(wbase + wl) * D_ + d0);
            *(float4*)&wr[4] = *(const float4*)(wdp + (size_t)(wbase + wl) * D_ + d0 + 4);
            #pragma unroll
            for (int i = 0; i < 4; ++i)
                #pragma unroll
                for (int j = 0; j < 8; ++j)
                    accd[i][j] = fmaf(vr[i], wr[j], accd[i][j]);
        }
    }

    #pragma unroll
    for (int i = 0; i < 4; ++i) {
        float4 o0 = make_float4(accd[i][0], accd[i][1], accd[i][2], accd[i][3]);
        float4 o1 = make_float4(accd[i][4], accd[i][5], accd[i][6], accd[i][7]);
        size_t base = ((size_t)(b * P_ + p0blk + pl0 + i)) * D_ + d0;
        *(float4*)(out + base)     = o0;
        *(float4*)(out + base + 4) = o1;
    }
}

// ---------------------------------------------------------------------------
extern "C" void kernel_launch(void* const* d_in, const int* in_sizes, int n_in,
                              void* d_out, int out_size, void* d_ws, size_t ws_size,
                              hipStream_t stream)
{
    const float* kv        = (const float*)d_in[0];
    const int*   positions = (const int*)d_in[1];
    const int*   rpos      = (const int*)d_in[2];
    // per level i: W_enc = d_in[3+3i], W_dec = d_in[4+3i], base = d_in[5+3i]

    float* ws     = (float*)d_ws;
    float* acc    = ws;                 // 3*BP = 23808 floats
    float* params = ws + 3 * BP;        // 3*BP
    float* wdp    = ws + 6 * BP;        // 496*128 = 63488 floats
    float* outf   = (float*)d_out;

    hipMemsetAsync(acc, 0, (size_t)(3 * BP) * sizeof(float), stream);

    pack_wdec<<<(CTOT * D_ + 255) / 256, 256, 0, stream>>>(
        (const float*)d_in[4], (const float*)d_in[7], (const float*)d_in[10],
        (const float*)d_in[13], (const float*)d_in[16], wdp);

    // level constants: n, S_eff (truncated EMA horizon), col offset, alpha, log2(1-alpha)
    const int   n_l[NLEV]    = {16, 32, 64, 128, 256};
    const int   seff_l[NLEV] = {4096, 4096, 1024, 512, 256};
    const int   coff_l[NLEV] = {0, 16, 48, 112, 240};
    const float a_l[NLEV]    = {0.001f, 0.005f, 0.02f, 0.05f, 0.1f};
    const float l2m_l[NLEV]  = {-0.0014434169f, -0.0072315692f, -0.0291463449f,
                                -0.0740005794f, -0.1520030934f};

    for (int l = 0; l < NLEV; ++l) {
        dim3 grid((3 * n_l[l] + 63) / 64, seff_l[l] / 128, B_);
        encoder<<<grid, 256, 0, stream>>>(
            kv, (const float*)d_in[3 + 3 * l], (const float*)d_in[5 + 3 * l],
            positions, acc, n_l[l], seff_l[l], coff_l[l], a_l[l], l2m_l[l]);
    }

    combine<<<(BP + 255) / 256, 256, 0, stream>>>(
        acc, params,
        (const float*)d_in[5], (const float*)d_in[8], (const float*)d_in[11],
        (const float*)d_in[14], (const float*)d_in[17]);

    decoder<<<dim3(P_ / 64, B_), 256, 0, stream>>>(params, wdp, rpos, outf);
}

// Round 2
// 205.081 us; speedup vs baseline: 3.4450x; 3.4450x over previous
//
#include <hip/hip_runtime.h>

typedef __attribute__((ext_vector_type(8))) short short8;
typedef __attribute__((ext_vector_type(4))) float floatx4;

#define NLEV 5
#define B_   16
#define S_   4096
#define D_   128
#define P_   4096
#define CTOT 496                 // 16+32+64+128+256
#define BP   (B_ * CTOT)
#define WPADG 512                // padded wave count for decoder K
#define CENC 1488                // total encoder columns (sum 3n)
#define INV2PI 0.15915494309189535f

// round-to-nearest-even float -> bf16
__device__ __forceinline__ unsigned short f2bf(float f) {
    unsigned u = __float_as_uint(f);
    u += 0x7fffu + ((u >> 16) & 1u);
    return (unsigned short)(u >> 16);
}
__device__ __forceinline__ unsigned int pack2(float a, float b) {
    return (unsigned int)f2bf(a) | ((unsigned int)f2bf(b) << 16);
}

// ---------------------------------------------------------------------------
// Pack weights to bf16:
//   wencb[c][d]  c in level-concat order (1488 x 128)  — B-frag rows for encoder
//   wdbT [d][w]  (128 x 512, w zero-padded 496->512)   — B-frag rows for decoder
// ---------------------------------------------------------------------------
__global__ void pack_weights(const float* __restrict__ we0, const float* __restrict__ we1,
                             const float* __restrict__ we2, const float* __restrict__ we3,
                             const float* __restrict__ we4,
                             const float* __restrict__ wd0, const float* __restrict__ wd1,
                             const float* __restrict__ wd2, const float* __restrict__ wd3,
                             const float* __restrict__ wd4,
                             unsigned short* __restrict__ wencb,
                             unsigned short* __restrict__ wdbT)
{
    int idx = blockIdx.x * 256 + threadIdx.x;
    const int NE = CENC * D_;                 // 190464
    if (idx < NE) {
        int c = idx >> 7, d = idx & 127;
        const float* src; int off;
        if (c < 48)        { src = we0; off = 0;   }
        else if (c < 144)  { src = we1; off = 48;  }
        else if (c < 336)  { src = we2; off = 144; }
        else               { src = (c < 720) ? we3 : we4; off = (c < 720) ? 336 : 720; }
        wencb[idx] = f2bf(src[(size_t)(c - off) * D_ + d]);
    } else {
        int k = idx - NE;
        if (k >= D_ * WPADG) return;
        int d = k >> 9, w = k & 511;
        float v = 0.0f;
        if (w < CTOT) {
            const float* src; int off, nl;
            if (w < 16)       { src = wd0; off = 0;   nl = 16;  }
            else if (w < 48)  { src = wd1; off = 16;  nl = 32;  }
            else if (w < 112) { src = wd2; off = 48;  nl = 64;  }
            else if (w < 240) { src = wd3; off = 112; nl = 128; }
            else              { src = wd4; off = 240; nl = 256; }
            v = src[(size_t)d * nl + (w - off)];
        }
        wdbT[k] = f2bf(v);
    }
}

// ---------------------------------------------------------------------------
// Fused encoder, all 5 levels. Block = (b, 64-t tile), hot t-tiles first.
// A = kv (t x d) bf16 frags cached in VGPRs; B = Wenc (d x c) 16B global loads.
// C layout (verified): col = lane&15 = c, row = quad*4+reg = t.
// Epilogue: per-reg EMA weight + kind transform, shfl t-reduce, atomicAdd.
// ---------------------------------------------------------------------------
__global__ __launch_bounds__(256) void encoder(
    const float* __restrict__ kv, const int* __restrict__ positions,
    const unsigned short* __restrict__ wencb,
    const float* __restrict__ bfr0, const float* __restrict__ bfr1,
    const float* __restrict__ bfr2, const float* __restrict__ bfr3,
    const float* __restrict__ bfr4,
    float* __restrict__ accb)
{
    __shared__ unsigned short kvb[64 * 136];   // [t][d] bf16, stride 136 (2-way free)
    __shared__ float pf[64];
    const int b   = blockIdx.y;
    const int t0  = S_ - 64 * (blockIdx.x + 1);   // hot (late-t) blocks dispatch first
    const int tid = threadIdx.x;

    // stage kv tile: fp32 float4 -> bf16 LDS
    const float* src = kv + ((size_t)(b * S_ + t0)) * D_;
    #pragma unroll
    for (int f = 0; f < 8; ++f) {
        int idx = f * 256 + tid;
        int t = idx >> 5, d4 = idx & 31;
        float4 val = *(const float4*)(src + t * D_ + d4 * 4);
        unsigned long long u = (unsigned long long)pack2(val.x, val.y)
                             | ((unsigned long long)pack2(val.z, val.w) << 32);
        *(unsigned long long*)&kvb[t * 136 + d4 * 4] = u;
    }
    if (tid < 64) pf[tid] = (float)positions[t0 + tid] * (1.0f / 8192.0f);
    __syncthreads();

    const int wid = tid >> 6, lane = tid & 63, ln = lane & 15, quad = lane >> 4;

    // cache all 16 A-frags (4 m-tiles x 4 k-steps) and per-lane pf(t)
    short8 afr[4][4];
    #pragma unroll
    for (int m = 0; m < 4; ++m)
        #pragma unroll
        for (int k = 0; k < 4; ++k)
            afr[m][k] = *(const short8*)&kvb[(m * 16 + ln) * 136 + k * 32 + quad * 8];
    float pfr[16];
    #pragma unroll
    for (int m = 0; m < 4; ++m)
        #pragma unroll
        for (int r = 0; r < 4; ++r)
            pfr[m * 4 + r] = pf[m * 16 + quad * 4 + r];

    const int   n_l[5]  = {16, 32, 64, 128, 256};
    const int   seff[5] = {4096, 4096, 1024, 512, 256};
    const int   coff[5] = {0, 16, 48, 112, 240};
    const int   c3[5]   = {0, 48, 144, 336, 720};
    const float al[5]   = {0.001f, 0.005f, 0.02f, 0.05f, 0.1f};
    const float l2m[5]  = {-0.0014434169f, -0.0072315692f, -0.0291463449f,
                           -0.0740005794f, -0.1520030934f};
    const float* bfp[5] = {bfr0, bfr1, bfr2, bfr3, bfr4};

    for (int l = 0; l < 5; ++l) {
        if (64 * (blockIdx.x + 1) > seff[l]) break;   // seff nonincreasing
        const int n = n_l[l];
        float wtr[16];
        #pragma unroll
        for (int i = 0; i < 16; ++i) {
            int tg = t0 + (i >> 2) * 16 + quad * 4 + (i & 3);
            wtr[i] = al[l] * exp2f((float)(S_ - 1 - tg) * l2m[l]);
        }
        const int nch = (3 * n) >> 4;
        for (int ci = wid; ci < nch; ci += 4) {
            const unsigned short* wrow = wencb + (size_t)(c3[l] + ci * 16 + ln) * D_;
            short8 bfg[4];
            #pragma unroll
            for (int k = 0; k < 4; ++k)
                bfg[k] = *(const short8*)(wrow + k * 32 + quad * 8);
            floatx4 acc[4];
            #pragma unroll
            for (int m = 0; m < 4; ++m) acc[m] = (floatx4){0.f, 0.f, 0.f, 0.f};
            #pragma unroll
            for (int k = 0; k < 4; ++k)
                #pragma unroll
                for (int m = 0; m < 4; ++m)
                    acc[m] = __builtin_amdgcn_mfma_f32_16x16x32_bf16(
                                 afr[m][k], bfg[k], acc[m], 0, 0, 0);

            const int kind  = (ci * 16) / n;          // chunk lies in one kind
            const int local = ci * 16 + ln - kind * n;
            const float bsv = (kind == 0) ? bfp[l][local] : 0.0f;
            float s = 0.0f;
            #pragma unroll
            for (int m = 0; m < 4; ++m)
                #pragma unroll
                for (int r = 0; r < 4; ++r) {
                    float v = acc[m][r];
                    if (kind == 0) {
                        float rev = bsv * pfr[m * 4 + r];   // sin(2pi*base*pos/8192)
                        rev -= floorf(rev);
                        v *= __builtin_amdgcn_sinf(rev);
                    } else if (kind == 1) {
                        v = fabsf(v);
                    }
                    s += wtr[m * 4 + r] * v;
                }
            s += __shfl_xor(s, 16);
            s += __shfl_xor(s, 32);
            if (lane < 16)
                atomicAdd(accb + (size_t)kind * BP + b * CTOT + coff[l] + local, s);
        }
    }
}

// ---------------------------------------------------------------------------
// Combine: padded per-b param arrays. rev = Q*rp/8192 + PHI/(2pi)
// ---------------------------------------------------------------------------
__global__ void combine(const float* __restrict__ accb,
                        float* __restrict__ parA, float* __restrict__ parQ,
                        float* __restrict__ parP,
                        const float* __restrict__ b0, const float* __restrict__ b1,
                        const float* __restrict__ b2, const float* __restrict__ b3,
                        const float* __restrict__ b4)
{
    int idx = blockIdx.x * 256 + threadIdx.x;
    if (idx >= B_ * WPADG) return;
    int b = idx >> 9, w = idx & 511;
    float A = 0.f, Q = 0.f, P = 0.f;
    if (w < CTOT) {
        const float* bf; int off;
        if (w < 16)       { bf = b0; off = 0;   }
        else if (w < 48)  { bf = b1; off = 16;  }
        else if (w < 112) { bf = b2; off = 48;  }
        else if (w < 240) { bf = b3; off = 112; }
        else              { bf = b4; off = 240; }
        float f  = accb[0 * BP + b * CTOT + w];
        A        = accb[1 * BP + b * CTOT + w];
        float ph = accb[2 * BP + b * CTOT + w];
        Q = f + bf[w - off];
        P = ph * INV2PI;
    }
    parA[idx] = A; parQ[idx] = Q; parP[idx] = P;
}

// ---------------------------------------------------------------------------
// Decoder: out[b,p,:] = sum_w A*sin(2pi*rev) * wd[w,:] via bf16 MFMA.
// Block: 64 p x 128 d, 4 waves split over d (2 n-tiles each, all 4 p-tiles).
// v [64][520] bf16 in LDS (A-operand), wdbT B-frags straight from global/L2.
// ---------------------------------------------------------------------------
__global__ __launch_bounds__(256) void decoder(
    const float* __restrict__ parA, const float* __restrict__ parQ,
    const float* __restrict__ parP,
    const unsigned short* __restrict__ wdbT, const int* __restrict__ rpos,
    float* __restrict__ out)
{
    __shared__ unsigned short v[64 * 520];
    __shared__ float rpn[64];
    const int b = blockIdx.y, p0 = blockIdx.x * 64, tid = threadIdx.x;
    if (tid < 64) rpn[tid] = (float)rpos[p0 + tid] * (1.0f / 8192.0f);

    // per-thread wave params, w = 2*tid, 2*tid+1
    float2 Q  = *(const float2*)(parQ + b * WPADG + 2 * tid);
    float2 A  = *(const float2*)(parA + b * WPADG + 2 * tid);
    float2 Ph = *(const float2*)(parP + b * WPADG + 2 * tid);
    __syncthreads();

    // generate v[p][w] bf16
    for (int p = 0; p < 64; ++p) {
        float rp = rpn[p];
        float r0 = fmaf(Q.x, rp, Ph.x); r0 -= floorf(r0);
        float r1 = fmaf(Q.y, rp, Ph.y); r1 -= floorf(r1);
        float v0 = A.x * __builtin_amdgcn_sinf(r0);
        float v1 = A.y * __builtin_amdgcn_sinf(r1);
        *(unsigned int*)&v[p * 520 + 2 * tid] = pack2(v0, v1);
    }
    __syncthreads();

    const int wid = tid >> 6, lane = tid & 63, ln = lane & 15, quad = lane >> 4;
    const int nt0 = wid * 2;

    floatx4 acc[4][2];
    #pragma unroll
    for (int m = 0; m < 4; ++m)
        #pragma unroll
        for (int j = 0; j < 2; ++j) acc[m][j] = (floatx4){0.f, 0.f, 0.f, 0.f};

    for (int k = 0; k < 16; ++k) {
        short8 bn[2];
        #pragma unroll
        for (int j = 0; j < 2; ++j)
            bn[j] = *(const short8*)(wdbT + (size_t)((nt0 + j) * 16 + ln) * WPADG
                                     + k * 32 + quad * 8);
        short8 am[4];
        #pragma unroll
        for (int m = 0; m < 4; ++m)
            am[m] = *(const short8*)&v[(m * 16 + ln) * 520 + k * 32 + quad * 8];
        #pragma unroll
        for (int m = 0; m < 4; ++m)
            #pragma unroll
            for (int j = 0; j < 2; ++j)
                acc[m][j] = __builtin_amdgcn_mfma_f32_16x16x32_bf16(
                                am[m], bn[j], acc[m][j], 0, 0, 0);
    }

    // store: col = lane&15 -> d, row = quad*4+reg -> p
    #pragma unroll
    for (int m = 0; m < 4; ++m)
        #pragma unroll
        for (int j = 0; j < 2; ++j)
            #pragma unroll
            for (int r = 0; r < 4; ++r) {
                int p = p0 + m * 16 + quad * 4 + r;
                int d = (nt0 + j) * 16 + ln;
                out[((size_t)(b * P_ + p)) * D_ + d] = acc[m][j][r];
            }
}

// ---------------------------------------------------------------------------
extern "C" void kernel_launch(void* const* d_in, const int* in_sizes, int n_in,
                              void* d_out, int out_size, void* d_ws, size_t ws_size,
                              hipStream_t stream)
{
    const float* kv        = (const float*)d_in[0];
    const int*   positions = (const int*)d_in[1];
    const int*   rpos      = (const int*)d_in[2];

    char* ws = (char*)d_ws;
    float*          accb  = (float*)(ws + 0);                 // 95232 B
    float*          parA  = (float*)(ws + 95232);             // 32768 B
    float*          parQ  = (float*)(ws + 128000);            // 32768 B
    float*          parP  = (float*)(ws + 160768);            // 32768 B
    unsigned short* wencb = (unsigned short*)(ws + 193536);   // 380928 B
    unsigned short* wdbT  = (unsigned short*)(ws + 574464);   // 131072 B

    hipMemsetAsync(accb, 0, (size_t)(3 * BP) * sizeof(float), stream);

    pack_weights<<<1000, 256, 0, stream>>>(
        (const float*)d_in[3], (const float*)d_in[6], (const float*)d_in[9],
        (const float*)d_in[12], (const float*)d_in[15],
        (const float*)d_in[4], (const float*)d_in[7], (const float*)d_in[10],
        (const float*)d_in[13], (const float*)d_in[16],
        wencb, wdbT);

    encoder<<<dim3(64, B_), 256, 0, stream>>>(
        kv, positions, wencb,
        (const float*)d_in[5], (const float*)d_in[8], (const float*)d_in[11],
        (const float*)d_in[14], (const float*)d_in[17],
        accb);

    combine<<<(B_ * WPADG) / 256, 256, 0, stream>>>(
        accb, parA, parQ, parP,
        (const float*)d_in[5], (const float*)d_in[8], (const float*)d_in[11],
        (const float*)d_in[14], (const float*)d_in[17]);

    decoder<<<dim3(P_ / 64, B_), 256, 0, stream>>>(
        parA, parQ, parP, wdbT, rpos, (float*)d_out);
}

// Round 3
// 161.732 us; speedup vs baseline: 4.3684x; 1.2680x over previous
//
#include <hip/hip_runtime.h>

typedef __attribute__((ext_vector_type(8))) short short8;
typedef __attribute__((ext_vector_type(4))) float floatx4;

#define NLEV 5
#define B_   16
#define S_   4096
#define D_   128
#define P_   4096
#define CTOT 496                 // 16+32+64+128+256
#define BP   (B_ * CTOT)
#define WPADG 512                // padded wave count for decoder K
#define CENC 1488                // total encoder columns (sum 3n)
#define INV2PI 0.15915494309189535f
#define NJBLK 336                // balanced encoder job-blocks per b

// round-to-nearest-even float -> bf16
__device__ __forceinline__ unsigned short f2bf(float f) {
    unsigned u = __float_as_uint(f);
    u += 0x7fffu + ((u >> 16) & 1u);
    return (unsigned short)(u >> 16);
}
__device__ __forceinline__ unsigned int pack2(float a, float b) {
    return (unsigned int)f2bf(a) | ((unsigned int)f2bf(b) << 16);
}

// ---------------------------------------------------------------------------
// Pack weights to bf16:
//   wencb[c][d]  c in level-concat order (1488 x 128)
//   wdbT [d][w]  (128 x 512, w zero-padded 496->512)
// ---------------------------------------------------------------------------
__global__ void pack_weights(const float* __restrict__ we0, const float* __restrict__ we1,
                             const float* __restrict__ we2, const float* __restrict__ we3,
                             const float* __restrict__ we4,
                             const float* __restrict__ wd0, const float* __restrict__ wd1,
                             const float* __restrict__ wd2, const float* __restrict__ wd3,
                             const float* __restrict__ wd4,
                             unsigned short* __restrict__ wencb,
                             unsigned short* __restrict__ wdbT)
{
    int idx = blockIdx.x * 256 + threadIdx.x;
    const int NE = CENC * D_;                 // 190464
    if (idx < NE) {
        int c = idx >> 7, d = idx & 127;
        const float* src; int off;
        if (c < 48)        { src = we0; off = 0;   }
        else if (c < 144)  { src = we1; off = 48;  }
        else if (c < 336)  { src = we2; off = 144; }
        else               { src = (c < 720) ? we3 : we4; off = (c < 720) ? 336 : 720; }
        wencb[idx] = f2bf(src[(size_t)(c - off) * D_ + d]);
    } else {
        int k = idx - NE;
        if (k >= D_ * WPADG) return;
        int d = k >> 9, w = k & 511;
        float v = 0.0f;
        if (w < CTOT) {
            const float* src; int off, nl;
            if (w < 16)       { src = wd0; off = 0;   nl = 16;  }
            else if (w < 48)  { src = wd1; off = 16;  nl = 32;  }
            else if (w < 112) { src = wd2; off = 48;  nl = 64;  }
            else if (w < 240) { src = wd3; off = 112; nl = 128; }
            else              { src = wd4; off = 240; nl = 256; }
            v = src[(size_t)d * nl + (w - off)];
        }
        wdbT[k] = f2bf(v);
    }
}

// ---------------------------------------------------------------------------
// Balanced fused encoder. Job = (t-tile bx, level l, 16-col chunk ci).
// Per b: chunks(bx) = 9 + [bx<16]*12 + [bx<8]*24 + [bx<4]*48 (levels with
// 64*(bx+1) <= seff participate; t0 = S - 64*(bx+1)). Blocks carry 4 chunks
// (1/wave): 24,12,6,3 blocks per bx -> 336 uniform blocks per b.
// C layout (verified): col = lane&15 = c, row = quad*4+reg = t.
// ---------------------------------------------------------------------------
__global__ __launch_bounds__(256) void encoder(
    const float* __restrict__ kv, const int* __restrict__ positions,
    const unsigned short* __restrict__ wencb,
    const float* __restrict__ bfr0, const float* __restrict__ bfr1,
    const float* __restrict__ bfr2, const float* __restrict__ bfr3,
    const float* __restrict__ bfr4,
    float* __restrict__ accb)
{
    __shared__ unsigned short kvb[64 * 136];   // [t][d] bf16, stride 136
    __shared__ float pf[64];
    const int b   = blockIdx.y;
    const int bid = blockIdx.x;
    const int tid = threadIdx.x;

    // decode (bx, local block) from balanced prefix
    int bx, lb;
    if (bid < 96)       { bx = bid / 24;            lb = bid % 24; }
    else if (bid < 144) { int r = bid - 96;  bx = 4 + r / 12; lb = r % 12; }
    else if (bid < 192) { int r = bid - 144; bx = 8 + r / 6;  lb = r % 6;  }
    else                { int r = bid - 192; bx = 16 + r / 3; lb = r % 3;  }
    const int t0 = S_ - 64 * (bx + 1);

    // stage kv tile: fp32 float4 -> bf16 LDS
    const float* src = kv + ((size_t)(b * S_ + t0)) * D_;
    #pragma unroll
    for (int f = 0; f < 8; ++f) {
        int idx = f * 256 + tid;
        int t = idx >> 5, d4 = idx & 31;
        float4 val = *(const float4*)(src + t * D_ + d4 * 4);
        unsigned long long u = (unsigned long long)pack2(val.x, val.y)
                             | ((unsigned long long)pack2(val.z, val.w) << 32);
        *(unsigned long long*)&kvb[t * 136 + d4 * 4] = u;
    }
    if (tid < 64) pf[tid] = (float)positions[t0 + tid] * (1.0f / 8192.0f);
    __syncthreads();

    const int wid = tid >> 6, lane = tid & 63, ln = lane & 15, quad = lane >> 4;

    // wave's job id -> (level, chunk)
    const int cnt = 9 + (bx < 16 ? 12 : 0) + (bx < 8 ? 24 : 0) + (bx < 4 ? 48 : 0);
    int jid = lb * 4 + wid;
    if (jid >= cnt) return;    // no barriers past this point

    const int   n_l[5]  = {16, 32, 64, 128, 256};
    const int   coff[5] = {0, 16, 48, 112, 240};
    const int   c3[5]   = {0, 48, 144, 336, 720};
    const float al[5]   = {0.001f, 0.005f, 0.02f, 0.05f, 0.1f};
    const float l2m[5]  = {-0.0014434169f, -0.0072315692f, -0.0291463449f,
                           -0.0740005794f, -0.1520030934f};
    const float* bfp[5] = {bfr0, bfr1, bfr2, bfr3, bfr4};

    int l = 0, ci = jid;
    {
        const int sz[5] = {3, 6, (bx < 16 ? 12 : 0), (bx < 8 ? 24 : 0), (bx < 4 ? 48 : 0)};
        #pragma unroll
        for (int q = 0; q < 4; ++q) {
            if (ci >= sz[l]) { ci -= sz[l]; ++l; }
        }
    }
    const int n = n_l[l];

    // GEMM: 16 t x 64t-rows? -> acc[m] over 4 m-tiles, K = 128 (4 ksteps)
    const unsigned short* wrow = wencb + (size_t)(c3[l] + ci * 16 + ln) * D_;
    floatx4 acc[4];
    #pragma unroll
    for (int m = 0; m < 4; ++m) acc[m] = (floatx4){0.f, 0.f, 0.f, 0.f};
    #pragma unroll
    for (int k = 0; k < 4; ++k) {
        short8 bfg = *(const short8*)(wrow + k * 32 + quad * 8);
        #pragma unroll
        for (int m = 0; m < 4; ++m) {
            short8 af = *(const short8*)&kvb[(m * 16 + ln) * 136 + k * 32 + quad * 8];
            acc[m] = __builtin_amdgcn_mfma_f32_16x16x32_bf16(af, bfg, acc[m], 0, 0, 0);
        }
    }

    // epilogue: EMA weight + kind transform, quad-reduce, atomic
    const int kind  = (ci * 16) / n;
    const int local = ci * 16 + ln - kind * n;
    const float bsv = (kind == 0) ? bfp[l][local] : 0.0f;
    float s = 0.0f;
    #pragma unroll
    for (int m = 0; m < 4; ++m)
        #pragma unroll
        for (int r = 0; r < 4; ++r) {
            int   trel = m * 16 + quad * 4 + r;
            int   tg   = t0 + trel;
            float wt   = al[l] * exp2f((float)(S_ - 1 - tg) * l2m[l]);
            float v    = acc[m][r];
            if (kind == 0) {
                float rev = bsv * pf[trel];     // sin(2pi * base * pos/8192)
                rev -= floorf(rev);
                v *= __builtin_amdgcn_sinf(rev);
            } else if (kind == 1) {
                v = fabsf(v);
            }
            s += wt * v;
        }
    s += __shfl_xor(s, 16);
    s += __shfl_xor(s, 32);
    if (lane < 16)
        atomicAdd(accb + (size_t)kind * BP + b * CTOT + coff[l] + local, s);
}

// ---------------------------------------------------------------------------
// Combine: padded per-b param arrays. rev = Q*rp/8192 + PHI/(2pi)
// ---------------------------------------------------------------------------
__global__ void combine(const float* __restrict__ accb,
                        float* __restrict__ parA, float* __restrict__ parQ,
                        float* __restrict__ parP,
                        const float* __restrict__ b0, const float* __restrict__ b1,
                        const float* __restrict__ b2, const float* __restrict__ b3,
                        const float* __restrict__ b4)
{
    int idx = blockIdx.x * 256 + threadIdx.x;
    if (idx >= B_ * WPADG) return;
    int b = idx >> 9, w = idx & 511;
    float A = 0.f, Q = 0.f, P = 0.f;
    if (w < CTOT) {
        const float* bf; int off;
        if (w < 16)       { bf = b0; off = 0;   }
        else if (w < 48)  { bf = b1; off = 16;  }
        else if (w < 112) { bf = b2; off = 48;  }
        else if (w < 240) { bf = b3; off = 112; }
        else              { bf = b4; off = 240; }
        float f  = accb[0 * BP + b * CTOT + w];
        A        = accb[1 * BP + b * CTOT + w];
        float ph = accb[2 * BP + b * CTOT + w];
        Q = f + bf[w - off];
        P = ph * INV2PI;
    }
    parA[idx] = A; parQ[idx] = Q; parP[idx] = P;
}

// ---------------------------------------------------------------------------
// Decoder: out[b,p,:] = sum_w A*sin(2pi*rev) * wd[w,:] via bf16 MFMA.
// Block 64p x 128d; K=512 split into 2 passes of 256 -> v[64][264] bf16
// (34 KB LDS, 4 blocks/CU). 4 waves split over d.
// ---------------------------------------------------------------------------
__global__ __launch_bounds__(256) void decoder(
    const float* __restrict__ parA, const float* __restrict__ parQ,
    const float* __restrict__ parP,
    const unsigned short* __restrict__ wdbT, const int* __restrict__ rpos,
    float* __restrict__ out)
{
    __shared__ unsigned short v[64 * 264];
    __shared__ float rpn[64];
    const int b = blockIdx.y, p0 = blockIdx.x * 64, tid = threadIdx.x;
    if (tid < 64) rpn[tid] = (float)rpos[p0 + tid] * (1.0f / 8192.0f);

    const int wid = tid >> 6, lane = tid & 63, ln = lane & 15, quad = lane >> 4;
    const int nt0 = wid * 2;

    floatx4 acc[4][2];
    #pragma unroll
    for (int m = 0; m < 4; ++m)
        #pragma unroll
        for (int j = 0; j < 2; ++j) acc[m][j] = (floatx4){0.f, 0.f, 0.f, 0.f};

    #pragma unroll
    for (int half = 0; half < 2; ++half) {
        const int w0 = half * 256;
        // per-thread column params (w = w0 + tid)
        float Q  = parQ[b * WPADG + w0 + tid];
        float A  = parA[b * WPADG + w0 + tid];
        float Ph = parP[b * WPADG + w0 + tid];
        __syncthreads();   // prior MFMA reads done (and rpn ready on pass 0)
        for (int p = 0; p < 64; ++p) {
            float r = fmaf(Q, rpn[p], Ph);
            r -= floorf(r);
            v[p * 264 + tid] = f2bf(A * __builtin_amdgcn_sinf(r));
        }
        __syncthreads();

        #pragma unroll
        for (int kk = 0; kk < 8; ++kk) {
            short8 bn[2];
            #pragma unroll
            for (int j = 0; j < 2; ++j)
                bn[j] = *(const short8*)(wdbT + (size_t)((nt0 + j) * 16 + ln) * WPADG
                                         + w0 + kk * 32 + quad * 8);
            short8 am[4];
            #pragma unroll
            for (int m = 0; m < 4; ++m)
                am[m] = *(const short8*)&v[(m * 16 + ln) * 264 + kk * 32 + quad * 8];
            #pragma unroll
            for (int m = 0; m < 4; ++m)
                #pragma unroll
                for (int j = 0; j < 2; ++j)
                    acc[m][j] = __builtin_amdgcn_mfma_f32_16x16x32_bf16(
                                    am[m], bn[j], acc[m][j], 0, 0, 0);
        }
    }

    // store: col = lane&15 -> d, row = quad*4+reg -> p
    #pragma unroll
    for (int m = 0; m < 4; ++m)
        #pragma unroll
        for (int j = 0; j < 2; ++j)
            #pragma unroll
            for (int r = 0; r < 4; ++r) {
                int p = p0 + m * 16 + quad * 4 + r;
                int d = (nt0 + j) * 16 + ln;
                out[((size_t)(b * P_ + p)) * D_ + d] = acc[m][j][r];
            }
}

// ---------------------------------------------------------------------------
extern "C" void kernel_launch(void* const* d_in, const int* in_sizes, int n_in,
                              void* d_out, int out_size, void* d_ws, size_t ws_size,
                              hipStream_t stream)
{
    const float* kv        = (const float*)d_in[0];
    const int*   positions = (const int*)d_in[1];
    const int*   rpos      = (const int*)d_in[2];

    char* ws = (char*)d_ws;
    float*          accb  = (float*)(ws + 0);                 // 95232 B
    float*          parA  = (float*)(ws + 95232);             // 32768 B
    float*          parQ  = (float*)(ws + 128000);            // 32768 B
    float*          parP  = (float*)(ws + 160768);            // 32768 B
    unsigned short* wencb = (unsigned short*)(ws + 193536);   // 380928 B
    unsigned short* wdbT  = (unsigned short*)(ws + 574464);   // 131072 B

    hipMemsetAsync(accb, 0, (size_t)(3 * BP) * sizeof(float), stream);

    pack_weights<<<1000, 256, 0, stream>>>(
        (const float*)d_in[3], (const float*)d_in[6], (const float*)d_in[9],
        (const float*)d_in[12], (const float*)d_in[15],
        (const float*)d_in[4], (const float*)d_in[7], (const float*)d_in[10],
        (const float*)d_in[13], (const float*)d_in[16],
        wencb, wdbT);

    encoder<<<dim3(NJBLK, B_), 256, 0, stream>>>(
        kv, positions, wencb,
        (const float*)d_in[5], (const float*)d_in[8], (const float*)d_in[11],
        (const float*)d_in[14], (const float*)d_in[17],
        accb);

    combine<<<(B_ * WPADG) / 256, 256, 0, stream>>>(
        accb, parA, parQ, parP,
        (const float*)d_in[5], (const float*)d_in[8], (const float*)d_in[11],
        (const float*)d_in[14], (const float*)d_in[17]);

    decoder<<<dim3(P_ / 64, B_), 256, 0, stream>>>(
        parA, parQ, parP, wdbT, rpos, (float*)d_out);
}